// Round 12
// baseline (239.441 us; speedup 1.0000x reference)
//
#include <hip/hip_runtime.h>
#include <hip/hip_bf16.h>

// ---------------------------------------------------------------------------
// SAGE-GCN x3 on MI355X.  Round 12.
//   9 kernels: init | bin | cntprep(+sort+scan+scatter fused) | 3x(gemm,agg).
//   Agg: XCC-resident quarter planes, uint4/lane gathers, windowed degree
//     sort, sentinel-padded branchless loop, persistent claim-loop blocks.
//   GEMM: MFMA 16x16x32 bf16, 2 row-sets/wave, nt-streamed (VGPR ~60 ->
//     32 waves/CU occupancy headroom).
//   CSR: bucketed 2-pass, int4-vectorized bin, fully fused prep.
// ---------------------------------------------------------------------------

#define NFEAT 128
#define BKT_CAP 12288
#define CHUNK 64

using bf16x8 = __attribute__((ext_vector_type(8))) short;
using f32x4  = __attribute__((ext_vector_type(4))) float;

__device__ __forceinline__ ushort f2bf(float f) {
    unsigned u = __float_as_uint(f);
    u = (u + 0x7fffu + ((u >> 16) & 1u)) >> 16;
    return (ushort)u;
}
__device__ __forceinline__ float bflo(unsigned v) { return __uint_as_float(v << 16); }
__device__ __forceinline__ float bfhi(unsigned v) { return __uint_as_float(v & 0xffff0000u); }

__device__ __forceinline__ int xcc_id() {
    int x;
    asm volatile("s_getreg_b32 %0, hwreg(HW_REG_XCC_ID)" : "=s"(x));
    return x & 7;
}

// ---------------- init: esrc sentinel fill + ctl zeros + plane sentinel rows
//                  + W0|W1|W2 -> bf16 cast (fused) ----------------

__global__ __launch_bounds__(256) void k_init(unsigned* __restrict__ esrc_u32, int fillN, unsigned sent2,
                                              int* __restrict__ ctl, ushort* __restrict__ Ybuf, int n,
                                              const float* __restrict__ W0, const float* __restrict__ W1,
                                              const float* __restrict__ W2, ushort* __restrict__ Wb) {
    int i = blockIdx.x * 256 + threadIdx.x;
    if (i < fillN) {
        esrc_u32[i] = sent2;
    } else if (i < fillN + 336) {
        ctl[i - fillN] = 0;
    } else if (i < fillN + 336 + 64) {
        int j = i - fillN - 336;      // 4 planes x 16 uints (64B sentinel row)
        int p = j >> 4, k = j & 15;
        ((unsigned*)(Ybuf + (size_t)p * (n + 1) * 32 + (size_t)n * 32))[k] = 0u;
    } else if (i < fillN + 336 + 64 + 40960) {
        int j = i - fillN - 336 - 64;
        float v = (j < 16384) ? W0[j] : ((j < 32768) ? W1[j - 16384] : W2[j - 32768]);
        Wb[j] = f2bf(v);
    }
}

// ---------------- CSR pass A: bin edges into 512-node buckets ----------------
// int4-vectorized src/dst loads (4 edges per load).

__global__ __launch_bounds__(256) void k_bin(const int* __restrict__ src, const int* __restrict__ dst,
                                             int* __restrict__ gcur, unsigned* __restrict__ pairs, int ne) {
    __shared__ int lcnt[128];
    __shared__ int lbase[128];
    int tid = threadIdx.x;
    if (tid < 128) lcnt[tid] = 0;
    __syncthreads();
    int e0 = blockIdx.x * 4096;
    int myrank[16];
    int mybkt[16];
    unsigned mypair[16];
    #pragma unroll
    for (int blk = 0; blk < 4; ++blk) {
        int e = e0 + blk * 1024 + tid * 4;
        int4 s4, d4;
        bool full = (e + 3 < ne);
        if (full) {
            s4 = *(const int4*)&src[e];
            d4 = *(const int4*)&dst[e];
        } else {
            s4.x = (e + 0 < ne) ? src[e + 0] : 0;  d4.x = (e + 0 < ne) ? dst[e + 0] : -1;
            s4.y = (e + 1 < ne) ? src[e + 1] : 0;  d4.y = (e + 1 < ne) ? dst[e + 1] : -1;
            s4.z = (e + 2 < ne) ? src[e + 2] : 0;  d4.z = (e + 2 < ne) ? dst[e + 2] : -1;
            s4.w = (e + 3 < ne) ? src[e + 3] : 0;  d4.w = (e + 3 < ne) ? dst[e + 3] : -1;
        }
        int ss[4] = {s4.x, s4.y, s4.z, s4.w};
        int dd[4] = {d4.x, d4.y, d4.z, d4.w};
        #pragma unroll
        for (int c = 0; c < 4; ++c) {
            int i = blk * 4 + c;
            if (dd[c] >= 0) {
                int b = dd[c] >> 9;
                mybkt[i]  = b;
                mypair[i] = (unsigned)(ss[c] & 0xffff) | ((unsigned)(dd[c] & 511) << 16);
                myrank[i] = atomicAdd(&lcnt[b], 1);
            } else mybkt[i] = -1;
        }
    }
    __syncthreads();
    if (tid < 128) lbase[tid] = lcnt[tid] ? atomicAdd(&gcur[tid], lcnt[tid]) : 0;
    __syncthreads();
    #pragma unroll
    for (int i = 0; i < 16; ++i) {
        if (mybkt[i] >= 0) {
            int pos = lbase[mybkt[i]] + myrank[i];
            if (pos < BKT_CAP) pairs[(size_t)mybkt[i] * BKT_CAP + pos] = mypair[i];
        }
    }
}

// ---------------- fused: count + degree-sort + padded scan + scatter ----------------
// One block = one 1024-node window (2 buckets).  All CSR finishing in one
// kernel: LDS counts -> cnt, counting-sort -> perm, 8-padded scan with
// atomic global base -> offs (LDS-resident), scatter pairs -> esrc.

__global__ __launch_bounds__(1024) void k_cntprep(const unsigned* __restrict__ pairs, const int* __restrict__ gcur,
                                                  int* __restrict__ cnt, int* __restrict__ perm,
                                                  int* __restrict__ offs, int* __restrict__ gbase,
                                                  ushort* __restrict__ esrc, int n) {
    __shared__ int lcnt[1024];    // counts, then reused as scatter cursors
    __shared__ int loffs[1024];
    __shared__ int hist[256];
    __shared__ int hcur[256];
    __shared__ int wtot[16];
    __shared__ int wpre[16];
    __shared__ int sbase;
    int tid  = threadIdx.x;
    int lane = tid & 63;
    int wv   = tid >> 6;
    int base = blockIdx.x * 1024;
    lcnt[tid] = 0;
    if (tid < 256) hist[tid] = 0;
    __syncthreads();
    #pragma unroll
    for (int h = 0; h < 2; ++h) {
        int bkt = blockIdx.x * 2 + h;
        int m = gcur[bkt];
        if (m > BKT_CAP) m = BKT_CAP;
        const unsigned* p = pairs + (size_t)bkt * BKT_CAP;
        for (int i = tid; i < m; i += 1024)
            atomicAdd(&lcnt[(int)(p[i] >> 16) + h * 512], 1);
    }
    __syncthreads();
    int i   = base + tid;
    bool act = i < n;
    int c = act ? lcnt[tid] : 0;
    if (act) cnt[i] = c;
    int d = c > 255 ? 255 : c;
    int rank = 0;
    if (act) rank = atomicAdd(&hist[d], 1);
    __syncthreads();
    {   // exclusive scan of hist[256] -> hcur; perm
        int v = (tid < 256) ? hist[tid] : 0;
        int val = v;
        #pragma unroll
        for (int off = 1; off < 64; off <<= 1) {
            int t = __shfl_up(val, off);
            if (lane >= off) val += t;
        }
        if (lane == 63) wtot[wv] = val;
        __syncthreads();
        if (tid == 0) {
            int s = 0;
            #pragma unroll
            for (int w = 0; w < 4; ++w) { wpre[w] = s; s += wtot[w]; }
        }
        __syncthreads();
        if (tid < 256) hcur[tid] = val - v + wpre[wv];
        __syncthreads();
        if (act) perm[base + hcur[d] + rank] = i;
        __syncthreads();
    }
    {   // 8-padded exclusive scan + atomic global base -> offs (global + LDS)
        int p8 = act ? ((c + 7) & ~7) : 0;
        int val = p8;
        #pragma unroll
        for (int off = 1; off < 64; off <<= 1) {
            int t = __shfl_up(val, off);
            if (lane >= off) val += t;
        }
        if (lane == 63) wtot[wv] = val;
        __syncthreads();
        if (tid == 0) {
            int s = 0;
            #pragma unroll
            for (int w = 0; w < 16; ++w) { wpre[w] = s; s += wtot[w]; }
            sbase = atomicAdd(gbase, s);
        }
        __syncthreads();
        int myoff = sbase + val - p8 + wpre[wv];
        if (act) offs[i] = myoff;
        loffs[tid] = myoff;
        lcnt[tid]  = 0;               // reuse as scatter cursor
    }
    __syncthreads();
    // scatter (pairs L2-warm from the counting pass)
    #pragma unroll
    for (int h = 0; h < 2; ++h) {
        int bkt = blockIdx.x * 2 + h;
        int m = gcur[bkt];
        if (m > BKT_CAP) m = BKT_CAP;
        const unsigned* p = pairs + (size_t)bkt * BKT_CAP;
        for (int j = tid; j < m; j += 1024) {
            unsigned pr = p[j];
            int w = (int)(pr >> 16) + h * 512;
            int r = atomicAdd(&lcnt[w], 1);
            esrc[loffs[w] + r] = (ushort)(pr & 0xffffu);
        }
    }
}

// ---------------- GEMM: planes_out[N/32][Mp][32] = X @ Wb^T ----------------
// 128 rows/block, 2 row-sets per wave sharing B frags; nt-streamed (no acc
// arrays) -> ~60 VGPR -> 32 waves/CU headroom.

template <typename InT, int N, bool PLANES_IN>
__global__ __launch_bounds__(256) void k_gemm_mfma(const InT* __restrict__ X, const ushort* __restrict__ Wb,
                                                   ushort* __restrict__ Y, int M, int Mp) {
    int w    = threadIdx.x >> 6;
    int lane = threadIdx.x & 63;
    int kb   = (lane >> 4) * 8;
    int rbase = blockIdx.x * 128 + w * 16 + (lane & 15);

    bf16x8 a0[4], a1[4];
    #pragma unroll
    for (int set = 0; set < 2; ++set) {
        int rowf = rbase + set * 64;
        bf16x8* a = set ? a1 : a0;
        if (rowf < M) {
            #pragma unroll
            for (int ks = 0; ks < 4; ++ks) {
                if constexpr (PLANES_IN) {
                    a[ks] = *(const bf16x8*)((const ushort*)X + (size_t)ks * Mp * 32 + (size_t)rowf * 32 + kb);
                } else {
                    const float* xp = (const float*)X + (size_t)rowf * 128 + ks * 32 + kb;
                    float4 f0 = *(const float4*)xp;
                    float4 f1 = *(const float4*)(xp + 4);
                    bf16x8 t;
                    t[0] = f2bf(f0.x); t[1] = f2bf(f0.y); t[2] = f2bf(f0.z); t[3] = f2bf(f0.w);
                    t[4] = f2bf(f1.x); t[5] = f2bf(f1.y); t[6] = f2bf(f1.z); t[7] = f2bf(f1.w);
                    a[ks] = t;
                }
            }
        } else {
            #pragma unroll
            for (int ks = 0; ks < 4; ++ks) {
                bf16x8 z = {0, 0, 0, 0, 0, 0, 0, 0};
                a[ks] = z;
            }
        }
    }

    constexpr int NT = N / 16;
    int c  = lane & 15;
    int rr = blockIdx.x * 128 + w * 16 + (lane >> 4) * 4;
    #pragma unroll
    for (int nt = 0; nt < NT; ++nt) {
        f32x4 acc0 = (f32x4){0.f, 0.f, 0.f, 0.f};
        f32x4 acc1 = (f32x4){0.f, 0.f, 0.f, 0.f};
        const ushort* wp = Wb + (size_t)(nt * 16 + (lane & 15)) * 128 + kb;
        #pragma unroll
        for (int ks = 0; ks < 4; ++ks) {
            bf16x8 b = *(const bf16x8*)(wp + ks * 32);
            acc0 = __builtin_amdgcn_mfma_f32_16x16x32_bf16(a0[ks], b, acc0, 0, 0, 0);
            acc1 = __builtin_amdgcn_mfma_f32_16x16x32_bf16(a1[ks], b, acc1, 0, 0, 0);
        }
        size_t pl = (size_t)(nt >> 1) * Mp * 32 + (nt & 1) * 16 + c;
        #pragma unroll
        for (int j = 0; j < 4; ++j) {
            int r = rr + j;
            if (r < M)      Y[pl + (size_t)r * 32]        = (ushort)f2bf(acc0[j]);
        }
        #pragma unroll
        for (int j = 0; j < 4; ++j) {
            int r = rr + 64 + j;
            if (r < M)      Y[pl + (size_t)r * 32]        = (ushort)f2bf(acc1[j]);
        }
    }
}

// ---------------- Aggregation (persistent claim-loop blocks) ----------------

#define ACC8(T)  { a0 += bflo((T).x); a1 += bfhi((T).x); a2 += bflo((T).y); a3 += bfhi((T).y); \
                   a4 += bflo((T).z); a5 += bfhi((T).z); a6 += bflo((T).w); a7 += bfhi((T).w); }

template <bool RELU>
__global__ __launch_bounds__(256) void k_agg128(const ushort* __restrict__ Yp, const int* __restrict__ offs,
                                                const int* __restrict__ cnt, const ushort* __restrict__ esrc,
                                                const float* __restrict__ bias, ushort* __restrict__ Zp,
                                                const int* __restrict__ perm, int* __restrict__ qh,
                                                int n, int nchunk) {
    __shared__ int sQ, sT;
    int lane = threadIdx.x & 63;
    int wv   = threadIdx.x >> 6;
    int g    = lane >> 2;
    int sub  = lane & 3;
    int pref = 0;
    if (threadIdx.x == 0) pref = xcc_id() & 3;

    while (true) {
        if (threadIdx.x == 0) {
            int t = -1, qsel = 0;
            #pragma unroll
            for (int a = 0; a < 4; ++a) {
                int cand = (pref + a) & 3;
                int tt = atomicAdd(&qh[cand * 16], 1);
                if (tt < nchunk) { qsel = cand; t = tt; break; }
            }
            sQ = qsel; sT = t;
        }
        __syncthreads();
        int q = sQ, t = sT;
        __syncthreads();
        if (t < 0) return;

        int idx  = t * CHUNK + wv * 16 + g;
        bool active = idx < n;
        int nd = 0, start = 0, deg = 0;
        if (active) {
            nd    = perm[idx];
            start = offs[nd];
            deg   = cnt[nd];
        }
        const uint4* Y4 = (const uint4*)(Yp + (size_t)q * (n + 1) * 32);
        uint4*       Z4 = (uint4*)(Zp + (size_t)q * (n + 1) * 32);

        float a0 = 0.f, a1 = 0.f, a2 = 0.f, a3 = 0.f, a4 = 0.f, a5 = 0.f, a6 = 0.f, a7 = 0.f;
        int nblk = active ? ((deg + 7) >> 3) : 0;
        const uint4* ep = (const uint4*)(esrc + start);
        uint4 ib = ep[0];
        #pragma unroll 2
        for (int b = 0; b < nblk; ++b) {
            uint4 ibn = ep[b + 1];
            unsigned s0 = ib.x & 0xffffu, s1 = ib.x >> 16;
            unsigned s2 = ib.y & 0xffffu, s3 = ib.y >> 16;
            unsigned s4 = ib.z & 0xffffu, s5 = ib.z >> 16;
            unsigned s6 = ib.w & 0xffffu, s7 = ib.w >> 16;
            uint4 t0 = Y4[(size_t)s0 * 4 + sub];
            uint4 t1 = Y4[(size_t)s1 * 4 + sub];
            uint4 t2 = Y4[(size_t)s2 * 4 + sub];
            uint4 t3 = Y4[(size_t)s3 * 4 + sub];
            uint4 t4 = Y4[(size_t)s4 * 4 + sub];
            uint4 t5 = Y4[(size_t)s5 * 4 + sub];
            uint4 t6 = Y4[(size_t)s6 * 4 + sub];
            uint4 t7 = Y4[(size_t)s7 * 4 + sub];
            ACC8(t0); ACC8(t1); ACC8(t2); ACC8(t3); ACC8(t4); ACC8(t5); ACC8(t6); ACC8(t7);
            ib = ibn;
        }

        if (active) {
            float scale = 1.0f / (float)(deg + 2);
            uint4 sf = Y4[(size_t)nd * 4 + sub];
            int f0 = q * 32 + sub * 8;
            float4 bA = *(const float4*)&bias[f0];
            float4 bB = *(const float4*)&bias[f0 + 4];
            float r0 = (a0 + 2.f * bflo(sf.x)) * scale + bA.x;
            float r1 = (a1 + 2.f * bfhi(sf.x)) * scale + bA.y;
            float r2 = (a2 + 2.f * bflo(sf.y)) * scale + bA.z;
            float r3 = (a3 + 2.f * bfhi(sf.y)) * scale + bA.w;
            float r4 = (a4 + 2.f * bflo(sf.z)) * scale + bB.x;
            float r5 = (a5 + 2.f * bfhi(sf.z)) * scale + bB.y;
            float r6 = (a6 + 2.f * bflo(sf.w)) * scale + bB.z;
            float r7 = (a7 + 2.f * bfhi(sf.w)) * scale + bB.w;
            if (RELU) {
                r0 = fmaxf(r0, 0.f); r1 = fmaxf(r1, 0.f); r2 = fmaxf(r2, 0.f); r3 = fmaxf(r3, 0.f);
                r4 = fmaxf(r4, 0.f); r5 = fmaxf(r5, 0.f); r6 = fmaxf(r6, 0.f); r7 = fmaxf(r7, 0.f);
            }
            uint4 o;
            o.x = (unsigned)f2bf(r0) | ((unsigned)f2bf(r1) << 16);
            o.y = (unsigned)f2bf(r2) | ((unsigned)f2bf(r3) << 16);
            o.z = (unsigned)f2bf(r4) | ((unsigned)f2bf(r5) << 16);
            o.w = (unsigned)f2bf(r6) | ((unsigned)f2bf(r7) << 16);
            Z4[(size_t)nd * 4 + sub] = o;
        }
        __syncthreads();
    }
}

__global__ __launch_bounds__(256) void k_agg64(const ushort* __restrict__ Yp, const int* __restrict__ offs,
                                               const int* __restrict__ cnt, const ushort* __restrict__ esrc,
                                               const float* __restrict__ bias, float* __restrict__ Z,
                                               const int* __restrict__ perm, int* __restrict__ qh,
                                               int n, int nchunk) {
    __shared__ int sQ, sT;
    int lane = threadIdx.x & 63;
    int wv   = threadIdx.x >> 6;
    int g    = lane >> 2;
    int sub  = lane & 3;
    int pref = 0;
    if (threadIdx.x == 0) pref = xcc_id() & 1;

    while (true) {
        if (threadIdx.x == 0) {
            int t = -1, qsel = 0;
            #pragma unroll
            for (int a = 0; a < 2; ++a) {
                int cand = (pref + a) & 1;
                int tt = atomicAdd(&qh[cand * 16], 1);
                if (tt < nchunk) { qsel = cand; t = tt; break; }
            }
            sQ = qsel; sT = t;
        }
        __syncthreads();
        int h = sQ, t = sT;
        __syncthreads();
        if (t < 0) return;

        int idx  = t * CHUNK + wv * 16 + g;
        bool active = idx < n;
        int nd = 0, start = 0, deg = 0;
        if (active) {
            nd    = perm[idx];
            start = offs[nd];
            deg   = cnt[nd];
        }
        const uint4* Y4 = (const uint4*)(Yp + (size_t)h * (n + 1) * 32);

        float a0 = 0.f, a1 = 0.f, a2 = 0.f, a3 = 0.f, a4 = 0.f, a5 = 0.f, a6 = 0.f, a7 = 0.f;
        int nblk = active ? ((deg + 7) >> 3) : 0;
        const uint4* ep = (const uint4*)(esrc + start);
        uint4 ib = ep[0];
        #pragma unroll 2
        for (int b = 0; b < nblk; ++b) {
            uint4 ibn = ep[b + 1];
            unsigned s0 = ib.x & 0xffffu, s1 = ib.x >> 16;
            unsigned s2 = ib.y & 0xffffu, s3 = ib.y >> 16;
            unsigned s4 = ib.z & 0xffffu, s5 = ib.z >> 16;
            unsigned s6 = ib.w & 0xffffu, s7 = ib.w >> 16;
            uint4 t0 = Y4[(size_t)s0 * 4 + sub];
            uint4 t1 = Y4[(size_t)s1 * 4 + sub];
            uint4 t2 = Y4[(size_t)s2 * 4 + sub];
            uint4 t3 = Y4[(size_t)s3 * 4 + sub];
            uint4 t4 = Y4[(size_t)s4 * 4 + sub];
            uint4 t5 = Y4[(size_t)s5 * 4 + sub];
            uint4 t6 = Y4[(size_t)s6 * 4 + sub];
            uint4 t7 = Y4[(size_t)s7 * 4 + sub];
            ACC8(t0); ACC8(t1); ACC8(t2); ACC8(t3); ACC8(t4); ACC8(t5); ACC8(t6); ACC8(t7);
            ib = ibn;
        }

        if (active) {
            float scale = 1.0f / (float)(deg + 2);
            uint4 sf = Y4[(size_t)nd * 4 + sub];
            int f0 = h * 32 + sub * 8;
            float4 bA = *(const float4*)&bias[f0];
            float4 bB = *(const float4*)&bias[f0 + 4];
            float4 oA, oB;
            oA.x = (a0 + 2.f * bflo(sf.x)) * scale + bA.x;
            oA.y = (a1 + 2.f * bfhi(sf.x)) * scale + bA.y;
            oA.z = (a2 + 2.f * bflo(sf.y)) * scale + bA.z;
            oA.w = (a3 + 2.f * bfhi(sf.y)) * scale + bA.w;
            oB.x = (a4 + 2.f * bflo(sf.z)) * scale + bB.x;
            oB.y = (a5 + 2.f * bfhi(sf.z)) * scale + bB.y;
            oB.z = (a6 + 2.f * bflo(sf.w)) * scale + bB.z;
            oB.w = (a7 + 2.f * bfhi(sf.w)) * scale + bB.w;
            float* zr = Z + (size_t)nd * 64 + f0;
            *(float4*)zr       = oA;
            *(float4*)(zr + 4) = oB;
        }
        __syncthreads();
    }
}

// ---------------- launch ----------------

extern "C" void kernel_launch(void* const* d_in, const int* in_sizes, int n_in,
                              void* d_out, int out_size, void* d_ws, size_t ws_size,
                              hipStream_t stream) {
    const float* in_feat = (const float*)d_in[0];
    const int*   src     = (const int*)d_in[1];
    const int*   dst     = (const int*)d_in[2];
    const float* W0      = (const float*)d_in[3];
    const float* b0      = (const float*)d_in[4];
    const float* W1      = (const float*)d_in[5];
    const float* b1      = (const float*)d_in[6];
    const float* W2      = (const float*)d_in[7];
    const float* b2      = (const float*)d_in[8];
    float* out = (float*)d_out;

    const int n  = in_sizes[0] / NFEAT;   // 50000 (<= 65535 assumed)
    const int ne = in_sizes[1];           // 800000
    const int nch = (n + 1023) / 1024;    // 49 windows (2 buckets each)
    const int nchunk = (n + CHUNK - 1) / CHUNK;
    const int escap = (ne + 8 * n + 31) & ~15;   // padded esrc capacity (ushorts)

    // workspace carve (16B aligned)
    int* offs       = (int*)d_ws;                          // n (+pad)
    int* gcur       = offs + ((n + 4) & ~3);               // 128 } ctl: 336 ints
    int* qh         = gcur + 128;                          // 192 }
    int* gbase      = qh + 192;                            // 16  }
    int* cnt        = gbase + 16;                          // n
    int* perm       = cnt + ((n + 3) & ~3);                // n
    unsigned* pairs = (unsigned*)(perm + ((n + 3) & ~3));  // 128*BKT_CAP
    ushort* esrc    = (ushort*)(pairs + (size_t)128 * BKT_CAP);  // escap
    ushort* Wb      = esrc + escap;                        // 40960
    ushort* Ybuf    = Wb + 40960;                          // (n+1)*128 plane-major
    ushort* Zbuf    = Ybuf + (size_t)(n + 1) * NFEAT;      // (n+1)*128 plane-major

    // --- init (esrc sentinels + ctl zeros + Ybuf sentinel rows + W cast) ---
    const int fillN = escap / 2;                           // uints
    const unsigned sent2 = ((unsigned)n << 16) | (unsigned)n;
    const int initN = fillN + 336 + 64 + 40960;
    k_init<<<(initN + 255) / 256, 256, 0, stream>>>((unsigned*)esrc, fillN, sent2, gcur, Ybuf, n,
                                                    W0, W1, W2, Wb);

    // --- CSR build (fully fused prep) ---
    k_bin<<<(ne + 4095) / 4096, 256, 0, stream>>>(src, dst, gcur, pairs, ne);
    k_cntprep<<<nch, 1024, 0, stream>>>(pairs, gcur, cnt, perm, offs, gbase, esrc, n);

    const ushort* Wb0 = Wb;
    const ushort* Wb1 = Wb + 16384;
    const ushort* Wb2 = Wb + 32768;

    const int gg = (n + 127) / 128;
    const int Mp = n + 1;

    // --- layer 0 ---
    k_gemm_mfma<float, 128, false><<<gg, 256, 0, stream>>>(in_feat, Wb0, Ybuf, n, Mp);
    k_agg128<true><<<2048, 256, 0, stream>>>(Ybuf, offs, cnt, esrc, b0, Zbuf, perm, qh, n, nchunk);
    // --- layer 1 ---
    k_gemm_mfma<ushort, 128, true><<<gg, 256, 0, stream>>>(Zbuf, Wb1, Ybuf, n, Mp);
    k_agg128<true><<<2048, 256, 0, stream>>>(Ybuf, offs, cnt, esrc, b1, Zbuf, perm, qh + 64, n, nchunk);
    // --- layer 2 (N=64, no relu, fp32 out) ---
    k_gemm_mfma<ushort, 64, true><<<gg, 256, 0, stream>>>(Zbuf, Wb2, Ybuf, n, Mp);
    k_agg64<<<1024, 256, 0, stream>>>(Ybuf, offs, cnt, esrc, b2, out, perm, qh + 128, n, nchunk);

    (void)ws_size; (void)n_in; (void)out_size;
}

// Round 13
// 189.680 us; speedup vs baseline: 1.2623x; 1.2623x over previous
//
#include <hip/hip_runtime.h>
#include <hip/hip_bf16.h>

// ---------------------------------------------------------------------------
// SAGE-GCN x3 on MI355X.  Round 13.
//   = Round 12 minus the persistent agg claim-loop (r12 evidence: barrier
//   convoy -> occupancy 54->33%, agg 30->62us).  Aggs back to r11's
//   one-claim-per-block.  Kept from r12: fused cntprep(+scatter), int4 bin,
//   nt-streamed GEMM (low VGPR).
//   9 kernels: init | bin | cntprep | 3x(gemm,agg).
// ---------------------------------------------------------------------------

#define NFEAT 128
#define BKT_CAP 12288
#define CHUNK 64

using bf16x8 = __attribute__((ext_vector_type(8))) short;
using f32x4  = __attribute__((ext_vector_type(4))) float;

__device__ __forceinline__ ushort f2bf(float f) {
    unsigned u = __float_as_uint(f);
    u = (u + 0x7fffu + ((u >> 16) & 1u)) >> 16;
    return (ushort)u;
}
__device__ __forceinline__ float bflo(unsigned v) { return __uint_as_float(v << 16); }
__device__ __forceinline__ float bfhi(unsigned v) { return __uint_as_float(v & 0xffff0000u); }

__device__ __forceinline__ int xcc_id() {
    int x;
    asm volatile("s_getreg_b32 %0, hwreg(HW_REG_XCC_ID)" : "=s"(x));
    return x & 7;
}

// ---------------- init ----------------

__global__ __launch_bounds__(256) void k_init(unsigned* __restrict__ esrc_u32, int fillN, unsigned sent2,
                                              int* __restrict__ ctl, ushort* __restrict__ Ybuf, int n,
                                              const float* __restrict__ W0, const float* __restrict__ W1,
                                              const float* __restrict__ W2, ushort* __restrict__ Wb) {
    int i = blockIdx.x * 256 + threadIdx.x;
    if (i < fillN) {
        esrc_u32[i] = sent2;
    } else if (i < fillN + 336) {
        ctl[i - fillN] = 0;
    } else if (i < fillN + 336 + 64) {
        int j = i - fillN - 336;      // 4 planes x 16 uints (64B sentinel row)
        int p = j >> 4, k = j & 15;
        ((unsigned*)(Ybuf + (size_t)p * (n + 1) * 32 + (size_t)n * 32))[k] = 0u;
    } else if (i < fillN + 336 + 64 + 40960) {
        int j = i - fillN - 336 - 64;
        float v = (j < 16384) ? W0[j] : ((j < 32768) ? W1[j - 16384] : W2[j - 32768]);
        Wb[j] = f2bf(v);
    }
}

// ---------------- CSR pass A: bin edges into 512-node buckets ----------------

__global__ __launch_bounds__(256) void k_bin(const int* __restrict__ src, const int* __restrict__ dst,
                                             int* __restrict__ gcur, unsigned* __restrict__ pairs, int ne) {
    __shared__ int lcnt[128];
    __shared__ int lbase[128];
    int tid = threadIdx.x;
    if (tid < 128) lcnt[tid] = 0;
    __syncthreads();
    int e0 = blockIdx.x * 4096;
    int myrank[16];
    int mybkt[16];
    unsigned mypair[16];
    #pragma unroll
    for (int blk = 0; blk < 4; ++blk) {
        int e = e0 + blk * 1024 + tid * 4;
        int4 s4, d4;
        bool full = (e + 3 < ne);
        if (full) {
            s4 = *(const int4*)&src[e];
            d4 = *(const int4*)&dst[e];
        } else {
            s4.x = (e + 0 < ne) ? src[e + 0] : 0;  d4.x = (e + 0 < ne) ? dst[e + 0] : -1;
            s4.y = (e + 1 < ne) ? src[e + 1] : 0;  d4.y = (e + 1 < ne) ? dst[e + 1] : -1;
            s4.z = (e + 2 < ne) ? src[e + 2] : 0;  d4.z = (e + 2 < ne) ? dst[e + 2] : -1;
            s4.w = (e + 3 < ne) ? src[e + 3] : 0;  d4.w = (e + 3 < ne) ? dst[e + 3] : -1;
        }
        int ss[4] = {s4.x, s4.y, s4.z, s4.w};
        int dd[4] = {d4.x, d4.y, d4.z, d4.w};
        #pragma unroll
        for (int c = 0; c < 4; ++c) {
            int i = blk * 4 + c;
            if (dd[c] >= 0) {
                int b = dd[c] >> 9;
                mybkt[i]  = b;
                mypair[i] = (unsigned)(ss[c] & 0xffff) | ((unsigned)(dd[c] & 511) << 16);
                myrank[i] = atomicAdd(&lcnt[b], 1);
            } else mybkt[i] = -1;
        }
    }
    __syncthreads();
    if (tid < 128) lbase[tid] = lcnt[tid] ? atomicAdd(&gcur[tid], lcnt[tid]) : 0;
    __syncthreads();
    #pragma unroll
    for (int i = 0; i < 16; ++i) {
        if (mybkt[i] >= 0) {
            int pos = lbase[mybkt[i]] + myrank[i];
            if (pos < BKT_CAP) pairs[(size_t)mybkt[i] * BKT_CAP + pos] = mypair[i];
        }
    }
}

// ---------------- fused: count + degree-sort + padded scan + scatter ----------------

__global__ __launch_bounds__(1024) void k_cntprep(const unsigned* __restrict__ pairs, const int* __restrict__ gcur,
                                                  int* __restrict__ cnt, int* __restrict__ perm,
                                                  int* __restrict__ offs, int* __restrict__ gbase,
                                                  ushort* __restrict__ esrc, int n) {
    __shared__ int lcnt[1024];    // counts, then reused as scatter cursors
    __shared__ int loffs[1024];
    __shared__ int hist[256];
    __shared__ int hcur[256];
    __shared__ int wtot[16];
    __shared__ int wpre[16];
    __shared__ int sbase;
    int tid  = threadIdx.x;
    int lane = tid & 63;
    int wv   = tid >> 6;
    int base = blockIdx.x * 1024;
    lcnt[tid] = 0;
    if (tid < 256) hist[tid] = 0;
    __syncthreads();
    #pragma unroll
    for (int h = 0; h < 2; ++h) {
        int bkt = blockIdx.x * 2 + h;
        int m = gcur[bkt];
        if (m > BKT_CAP) m = BKT_CAP;
        const unsigned* p = pairs + (size_t)bkt * BKT_CAP;
        for (int i = tid; i < m; i += 1024)
            atomicAdd(&lcnt[(int)(p[i] >> 16) + h * 512], 1);
    }
    __syncthreads();
    int i   = base + tid;
    bool act = i < n;
    int c = act ? lcnt[tid] : 0;
    if (act) cnt[i] = c;
    int d = c > 255 ? 255 : c;
    int rank = 0;
    if (act) rank = atomicAdd(&hist[d], 1);
    __syncthreads();
    {   // exclusive scan of hist[256] -> hcur; perm
        int v = (tid < 256) ? hist[tid] : 0;
        int val = v;
        #pragma unroll
        for (int off = 1; off < 64; off <<= 1) {
            int t = __shfl_up(val, off);
            if (lane >= off) val += t;
        }
        if (lane == 63) wtot[wv] = val;
        __syncthreads();
        if (tid == 0) {
            int s = 0;
            #pragma unroll
            for (int w = 0; w < 4; ++w) { wpre[w] = s; s += wtot[w]; }
        }
        __syncthreads();
        if (tid < 256) hcur[tid] = val - v + wpre[wv];
        __syncthreads();
        if (act) perm[base + hcur[d] + rank] = i;
        __syncthreads();
    }
    {   // 8-padded exclusive scan + atomic global base -> offs (global + LDS)
        int p8 = act ? ((c + 7) & ~7) : 0;
        int val = p8;
        #pragma unroll
        for (int off = 1; off < 64; off <<= 1) {
            int t = __shfl_up(val, off);
            if (lane >= off) val += t;
        }
        if (lane == 63) wtot[wv] = val;
        __syncthreads();
        if (tid == 0) {
            int s = 0;
            #pragma unroll
            for (int w = 0; w < 16; ++w) { wpre[w] = s; s += wtot[w]; }
            sbase = atomicAdd(gbase, s);
        }
        __syncthreads();
        int myoff = sbase + val - p8 + wpre[wv];
        if (act) offs[i] = myoff;
        loffs[tid] = myoff;
        lcnt[tid]  = 0;               // reuse as scatter cursor
    }
    __syncthreads();
    // scatter (pairs L2-warm from the counting pass)
    #pragma unroll
    for (int h = 0; h < 2; ++h) {
        int bkt = blockIdx.x * 2 + h;
        int m = gcur[bkt];
        if (m > BKT_CAP) m = BKT_CAP;
        const unsigned* p = pairs + (size_t)bkt * BKT_CAP;
        for (int j = tid; j < m; j += 1024) {
            unsigned pr = p[j];
            int w = (int)(pr >> 16) + h * 512;
            int r = atomicAdd(&lcnt[w], 1);
            esrc[loffs[w] + r] = (ushort)(pr & 0xffffu);
        }
    }
}

// ---------------- GEMM: planes_out[N/32][Mp][32] = X @ Wb^T ----------------
// 128 rows/block, 2 row-sets per wave sharing B frags; nt-streamed.

template <typename InT, int N, bool PLANES_IN>
__global__ __launch_bounds__(256) void k_gemm_mfma(const InT* __restrict__ X, const ushort* __restrict__ Wb,
                                                   ushort* __restrict__ Y, int M, int Mp) {
    int w    = threadIdx.x >> 6;
    int lane = threadIdx.x & 63;
    int kb   = (lane >> 4) * 8;
    int rbase = blockIdx.x * 128 + w * 16 + (lane & 15);

    bf16x8 a0[4], a1[4];
    #pragma unroll
    for (int set = 0; set < 2; ++set) {
        int rowf = rbase + set * 64;
        bf16x8* a = set ? a1 : a0;
        if (rowf < M) {
            #pragma unroll
            for (int ks = 0; ks < 4; ++ks) {
                if constexpr (PLANES_IN) {
                    a[ks] = *(const bf16x8*)((const ushort*)X + (size_t)ks * Mp * 32 + (size_t)rowf * 32 + kb);
                } else {
                    const float* xp = (const float*)X + (size_t)rowf * 128 + ks * 32 + kb;
                    float4 f0 = *(const float4*)xp;
                    float4 f1 = *(const float4*)(xp + 4);
                    bf16x8 t;
                    t[0] = f2bf(f0.x); t[1] = f2bf(f0.y); t[2] = f2bf(f0.z); t[3] = f2bf(f0.w);
                    t[4] = f2bf(f1.x); t[5] = f2bf(f1.y); t[6] = f2bf(f1.z); t[7] = f2bf(f1.w);
                    a[ks] = t;
                }
            }
        } else {
            #pragma unroll
            for (int ks = 0; ks < 4; ++ks) {
                bf16x8 z = {0, 0, 0, 0, 0, 0, 0, 0};
                a[ks] = z;
            }
        }
    }

    constexpr int NT = N / 16;
    int c  = lane & 15;
    int rr = blockIdx.x * 128 + w * 16 + (lane >> 4) * 4;
    #pragma unroll
    for (int nt = 0; nt < NT; ++nt) {
        f32x4 acc0 = (f32x4){0.f, 0.f, 0.f, 0.f};
        f32x4 acc1 = (f32x4){0.f, 0.f, 0.f, 0.f};
        const ushort* wp = Wb + (size_t)(nt * 16 + (lane & 15)) * 128 + kb;
        #pragma unroll
        for (int ks = 0; ks < 4; ++ks) {
            bf16x8 b = *(const bf16x8*)(wp + ks * 32);
            acc0 = __builtin_amdgcn_mfma_f32_16x16x32_bf16(a0[ks], b, acc0, 0, 0, 0);
            acc1 = __builtin_amdgcn_mfma_f32_16x16x32_bf16(a1[ks], b, acc1, 0, 0, 0);
        }
        size_t pl = (size_t)(nt >> 1) * Mp * 32 + (nt & 1) * 16 + c;
        #pragma unroll
        for (int j = 0; j < 4; ++j) {
            int r = rr + j;
            if (r < M) Y[pl + (size_t)r * 32] = (ushort)f2bf(acc0[j]);
        }
        #pragma unroll
        for (int j = 0; j < 4; ++j) {
            int r = rr + 64 + j;
            if (r < M) Y[pl + (size_t)r * 32] = (ushort)f2bf(acc1[j]);
        }
    }
}

// ---------------- Aggregation (one claim per block — r11 structure) ----------------

#define ACC8(T)  { a0 += bflo((T).x); a1 += bfhi((T).x); a2 += bflo((T).y); a3 += bfhi((T).y); \
                   a4 += bflo((T).z); a5 += bfhi((T).z); a6 += bflo((T).w); a7 += bfhi((T).w); }

template <bool RELU>
__global__ __launch_bounds__(256) void k_agg128(const ushort* __restrict__ Yp, const int* __restrict__ offs,
                                                const int* __restrict__ cnt, const ushort* __restrict__ esrc,
                                                const float* __restrict__ bias, ushort* __restrict__ Zp,
                                                const int* __restrict__ perm, int* __restrict__ qh,
                                                int n, int nchunk) {
    __shared__ int sQ, sT;
    if (threadIdx.x == 0) {
        int pref = xcc_id() & 3;
        int t = -1, qsel = 0;
        #pragma unroll
        for (int a = 0; a < 4; ++a) {
            int cand = (pref + a) & 3;
            int tt = atomicAdd(&qh[cand * 16], 1);
            if (tt < nchunk) { qsel = cand; t = tt; break; }
        }
        sQ = qsel; sT = t;
    }
    __syncthreads();
    int q = sQ, t = sT;
    if (t < 0) return;
    int lane = threadIdx.x & 63;
    int wv   = threadIdx.x >> 6;
    int g    = lane >> 2;
    int sub  = lane & 3;
    int idx  = t * CHUNK + wv * 16 + g;
    bool active = idx < n;
    int nd = 0, start = 0, deg = 0;
    if (active) {
        nd    = perm[idx];
        start = offs[nd];
        deg   = cnt[nd];
    }
    const uint4* Y4 = (const uint4*)(Yp + (size_t)q * (n + 1) * 32);
    uint4*       Z4 = (uint4*)(Zp + (size_t)q * (n + 1) * 32);

    float a0 = 0.f, a1 = 0.f, a2 = 0.f, a3 = 0.f, a4 = 0.f, a5 = 0.f, a6 = 0.f, a7 = 0.f;

    int nblk = active ? ((deg + 7) >> 3) : 0;
    const uint4* ep = (const uint4*)(esrc + start);
    uint4 ib = ep[0];
    #pragma unroll 2
    for (int b = 0; b < nblk; ++b) {
        uint4 ibn = ep[b + 1];
        unsigned s0 = ib.x & 0xffffu, s1 = ib.x >> 16;
        unsigned s2 = ib.y & 0xffffu, s3 = ib.y >> 16;
        unsigned s4 = ib.z & 0xffffu, s5 = ib.z >> 16;
        unsigned s6 = ib.w & 0xffffu, s7 = ib.w >> 16;
        uint4 t0 = Y4[(size_t)s0 * 4 + sub];
        uint4 t1 = Y4[(size_t)s1 * 4 + sub];
        uint4 t2 = Y4[(size_t)s2 * 4 + sub];
        uint4 t3 = Y4[(size_t)s3 * 4 + sub];
        uint4 t4 = Y4[(size_t)s4 * 4 + sub];
        uint4 t5 = Y4[(size_t)s5 * 4 + sub];
        uint4 t6 = Y4[(size_t)s6 * 4 + sub];
        uint4 t7 = Y4[(size_t)s7 * 4 + sub];
        ACC8(t0); ACC8(t1); ACC8(t2); ACC8(t3); ACC8(t4); ACC8(t5); ACC8(t6); ACC8(t7);
        ib = ibn;
    }

    if (active) {
        float scale = 1.0f / (float)(deg + 2);
        uint4 sf = Y4[(size_t)nd * 4 + sub];
        int f0 = q * 32 + sub * 8;
        float4 bA = *(const float4*)&bias[f0];
        float4 bB = *(const float4*)&bias[f0 + 4];
        float r0 = (a0 + 2.f * bflo(sf.x)) * scale + bA.x;
        float r1 = (a1 + 2.f * bfhi(sf.x)) * scale + bA.y;
        float r2 = (a2 + 2.f * bflo(sf.y)) * scale + bA.z;
        float r3 = (a3 + 2.f * bfhi(sf.y)) * scale + bA.w;
        float r4 = (a4 + 2.f * bflo(sf.z)) * scale + bB.x;
        float r5 = (a5 + 2.f * bfhi(sf.z)) * scale + bB.y;
        float r6 = (a6 + 2.f * bflo(sf.w)) * scale + bB.z;
        float r7 = (a7 + 2.f * bfhi(sf.w)) * scale + bB.w;
        if (RELU) {
            r0 = fmaxf(r0, 0.f); r1 = fmaxf(r1, 0.f); r2 = fmaxf(r2, 0.f); r3 = fmaxf(r3, 0.f);
            r4 = fmaxf(r4, 0.f); r5 = fmaxf(r5, 0.f); r6 = fmaxf(r6, 0.f); r7 = fmaxf(r7, 0.f);
        }
        uint4 o;
        o.x = (unsigned)f2bf(r0) | ((unsigned)f2bf(r1) << 16);
        o.y = (unsigned)f2bf(r2) | ((unsigned)f2bf(r3) << 16);
        o.z = (unsigned)f2bf(r4) | ((unsigned)f2bf(r5) << 16);
        o.w = (unsigned)f2bf(r6) | ((unsigned)f2bf(r7) << 16);
        Z4[(size_t)nd * 4 + sub] = o;
    }
}

__global__ __launch_bounds__(256) void k_agg64(const ushort* __restrict__ Yp, const int* __restrict__ offs,
                                               const int* __restrict__ cnt, const ushort* __restrict__ esrc,
                                               const float* __restrict__ bias, float* __restrict__ Z,
                                               const int* __restrict__ perm, int* __restrict__ qh,
                                               int n, int nchunk) {
    __shared__ int sQ, sT;
    if (threadIdx.x == 0) {
        int pref = xcc_id() & 1;
        int t = -1, qsel = 0;
        #pragma unroll
        for (int a = 0; a < 2; ++a) {
            int cand = (pref + a) & 1;
            int tt = atomicAdd(&qh[cand * 16], 1);
            if (tt < nchunk) { qsel = cand; t = tt; break; }
        }
        sQ = qsel; sT = t;
    }
    __syncthreads();
    int h = sQ, t = sT;
    if (t < 0) return;
    int lane = threadIdx.x & 63;
    int wv   = threadIdx.x >> 6;
    int g    = lane >> 2;
    int sub  = lane & 3;
    int idx  = t * CHUNK + wv * 16 + g;
    bool active = idx < n;
    int nd = 0, start = 0, deg = 0;
    if (active) {
        nd    = perm[idx];
        start = offs[nd];
        deg   = cnt[nd];
    }
    const uint4* Y4 = (const uint4*)(Yp + (size_t)h * (n + 1) * 32);

    float a0 = 0.f, a1 = 0.f, a2 = 0.f, a3 = 0.f, a4 = 0.f, a5 = 0.f, a6 = 0.f, a7 = 0.f;

    int nblk = active ? ((deg + 7) >> 3) : 0;
    const uint4* ep = (const uint4*)(esrc + start);
    uint4 ib = ep[0];
    #pragma unroll 2
    for (int b = 0; b < nblk; ++b) {
        uint4 ibn = ep[b + 1];
        unsigned s0 = ib.x & 0xffffu, s1 = ib.x >> 16;
        unsigned s2 = ib.y & 0xffffu, s3 = ib.y >> 16;
        unsigned s4 = ib.z & 0xffffu, s5 = ib.z >> 16;
        unsigned s6 = ib.w & 0xffffu, s7 = ib.w >> 16;
        uint4 t0 = Y4[(size_t)s0 * 4 + sub];
        uint4 t1 = Y4[(size_t)s1 * 4 + sub];
        uint4 t2 = Y4[(size_t)s2 * 4 + sub];
        uint4 t3 = Y4[(size_t)s3 * 4 + sub];
        uint4 t4 = Y4[(size_t)s4 * 4 + sub];
        uint4 t5 = Y4[(size_t)s5 * 4 + sub];
        uint4 t6 = Y4[(size_t)s6 * 4 + sub];
        uint4 t7 = Y4[(size_t)s7 * 4 + sub];
        ACC8(t0); ACC8(t1); ACC8(t2); ACC8(t3); ACC8(t4); ACC8(t5); ACC8(t6); ACC8(t7);
        ib = ibn;
    }

    if (active) {
        float scale = 1.0f / (float)(deg + 2);
        uint4 sf = Y4[(size_t)nd * 4 + sub];
        int f0 = h * 32 + sub * 8;
        float4 bA = *(const float4*)&bias[f0];
        float4 bB = *(const float4*)&bias[f0 + 4];
        float4 oA, oB;
        oA.x = (a0 + 2.f * bflo(sf.x)) * scale + bA.x;
        oA.y = (a1 + 2.f * bfhi(sf.x)) * scale + bA.y;
        oA.z = (a2 + 2.f * bflo(sf.y)) * scale + bA.z;
        oA.w = (a3 + 2.f * bfhi(sf.y)) * scale + bA.w;
        oB.x = (a4 + 2.f * bflo(sf.z)) * scale + bB.x;
        oB.y = (a5 + 2.f * bfhi(sf.z)) * scale + bB.y;
        oB.z = (a6 + 2.f * bflo(sf.w)) * scale + bB.z;
        oB.w = (a7 + 2.f * bfhi(sf.w)) * scale + bB.w;
        float* zr = Z + (size_t)nd * 64 + f0;
        *(float4*)zr       = oA;
        *(float4*)(zr + 4) = oB;
    }
}

// ---------------- launch ----------------

extern "C" void kernel_launch(void* const* d_in, const int* in_sizes, int n_in,
                              void* d_out, int out_size, void* d_ws, size_t ws_size,
                              hipStream_t stream) {
    const float* in_feat = (const float*)d_in[0];
    const int*   src     = (const int*)d_in[1];
    const int*   dst     = (const int*)d_in[2];
    const float* W0      = (const float*)d_in[3];
    const float* b0      = (const float*)d_in[4];
    const float* W1      = (const float*)d_in[5];
    const float* b1      = (const float*)d_in[6];
    const float* W2      = (const float*)d_in[7];
    const float* b2      = (const float*)d_in[8];
    float* out = (float*)d_out;

    const int n  = in_sizes[0] / NFEAT;   // 50000 (<= 65535 assumed)
    const int ne = in_sizes[1];           // 800000
    const int nch = (n + 1023) / 1024;    // windows (2 buckets each)
    const int nchunk = (n + CHUNK - 1) / CHUNK;
    const int escap = (ne + 8 * n + 31) & ~15;   // padded esrc capacity (ushorts)

    // workspace carve (16B aligned)
    int* offs       = (int*)d_ws;                          // n (+pad)
    int* gcur       = offs + ((n + 4) & ~3);               // 128 } ctl: 336 ints
    int* qh         = gcur + 128;                          // 192 }
    int* gbase      = qh + 192;                            // 16  }
    int* cnt        = gbase + 16;                          // n
    int* perm       = cnt + ((n + 3) & ~3);                // n
    unsigned* pairs = (unsigned*)(perm + ((n + 3) & ~3));  // 128*BKT_CAP
    ushort* esrc    = (ushort*)(pairs + (size_t)128 * BKT_CAP);  // escap
    ushort* Wb      = esrc + escap;                        // 40960
    ushort* Ybuf    = Wb + 40960;                          // (n+1)*128 plane-major
    ushort* Zbuf    = Ybuf + (size_t)(n + 1) * NFEAT;      // (n+1)*128 plane-major

    // --- init (esrc sentinels + ctl zeros + Ybuf sentinel rows + W cast) ---
    const int fillN = escap / 2;                           // uints
    const unsigned sent2 = ((unsigned)n << 16) | (unsigned)n;
    const int initN = fillN + 336 + 64 + 40960;
    k_init<<<(initN + 255) / 256, 256, 0, stream>>>((unsigned*)esrc, fillN, sent2, gcur, Ybuf, n,
                                                    W0, W1, W2, Wb);

    // --- CSR build (fully fused prep) ---
    k_bin<<<(ne + 4095) / 4096, 256, 0, stream>>>(src, dst, gcur, pairs, ne);
    k_cntprep<<<nch, 1024, 0, stream>>>(pairs, gcur, cnt, perm, offs, gbase, esrc, n);

    const ushort* Wb0 = Wb;
    const ushort* Wb1 = Wb + 16384;
    const ushort* Wb2 = Wb + 32768;

    const int gg = (n + 127) / 128;
    const int Mp = n + 1;

    // --- layer 0 ---
    k_gemm_mfma<float, 128, false><<<gg, 256, 0, stream>>>(in_feat, Wb0, Ybuf, n, Mp);
    k_agg128<true><<<4 * nchunk, 256, 0, stream>>>(Ybuf, offs, cnt, esrc, b0, Zbuf, perm, qh, n, nchunk);
    // --- layer 1 ---
    k_gemm_mfma<ushort, 128, true><<<gg, 256, 0, stream>>>(Zbuf, Wb1, Ybuf, n, Mp);
    k_agg128<true><<<4 * nchunk, 256, 0, stream>>>(Ybuf, offs, cnt, esrc, b1, Zbuf, perm, qh + 64, n, nchunk);
    // --- layer 2 (N=64, no relu, fp32 out) ---
    k_gemm_mfma<ushort, 64, true><<<gg, 256, 0, stream>>>(Zbuf, Wb2, Ybuf, n, Mp);
    k_agg64<<<2 * nchunk, 256, 0, stream>>>(Ybuf, offs, cnt, esrc, b2, out, perm, qh + 128, n, nchunk);

    (void)ws_size; (void)n_in; (void)out_size;
}